// Round 1
// baseline (327.008 us; speedup 1.0000x reference)
//
#include <hip/hip_runtime.h>
#include <hip/hip_bf16.h>

typedef float floatx4 __attribute__((ext_vector_type(4)));
typedef short shortx8 __attribute__((ext_vector_type(8)));
typedef short shortx4 __attribute__((ext_vector_type(4)));

#define CFENCE() asm volatile("" ::: "memory")

__device__ __forceinline__ float bf2f(short s) {
    union { unsigned u; float f; } cv;
    cv.u = ((unsigned)(unsigned short)s) << 16;
    return cv.f;
}
__device__ __forceinline__ short f2bf(float f) {
    union { float f; unsigned u; } cv; cv.f = f;
    unsigned r = (cv.u + 0x7fffu + ((cv.u >> 16) & 1u)) >> 16;
    return (short)r;
}

// ---------------- K0a: weights -> bf16 fragment-major layout ----------------
// wqkv_f: 384 frags (n16 0..47, kt 0..7), each 64 lanes x 8 shorts contiguous (1KB)
// wo_f:   128 frags (n16 0..15, kt 0..7)
// frag element: B[n = n16*16 + (lane&15)][k = kt*32 + (lane>>4)*8 + j]
__global__ __launch_bounds__(256) void wtrans(const float* __restrict__ Wq,
                                              const float* __restrict__ Wk,
                                              const float* __restrict__ Wv,
                                              const float* __restrict__ Wo,
                                              short* __restrict__ wqkv_f,
                                              short* __restrict__ wo_f) {
    int gtid = blockIdx.x * 256 + threadIdx.x;
    int f = gtid >> 6, lane = gtid & 63;
    int quad = lane >> 4, l15 = lane & 15;
    if (f < 384) {
        int n16 = f >> 3, kt = f & 7;
        int n = n16 * 16 + l15, z = n >> 8, ncol = n & 255;
        const float* src = (z == 0) ? Wq : (z == 1) ? Wk : Wv;
        shortx8 s;
#pragma unroll
        for (int j = 0; j < 8; ++j)
            s[j] = f2bf(src[(size_t)(kt * 32 + quad * 8 + j) * 256 + ncol]);
        *(shortx8*)(wqkv_f + (size_t)f * 512 + lane * 8) = s;
    } else {
        int f2 = f - 384;
        int n16 = f2 >> 3, kt = f2 & 7;
        int n = n16 * 16 + l15;
        shortx8 s;
#pragma unroll
        for (int j = 0; j < 8; ++j)
            s[j] = f2bf(Wo[(size_t)(kt * 32 + quad * 8 + j) * 256 + n]);
        *(shortx8*)(wo_f + (size_t)f2 * 512 + lane * 8) = s;
    }
}

// ---------------- K0b: CPB MLP, one block per table entry ----------------
__device__ __forceinline__ float sgnlog(float x) {
    return copysignf(__log2f(fabsf(x) + 1.f) / 3.f, x);
}
__global__ __launch_bounds__(256) void bias_mlp(const float* __restrict__ ls,
                                                const float* __restrict__ w1,
                                                const float* __restrict__ b1,
                                                const float* __restrict__ w2,
                                                float* __restrict__ b225g,
                                                float* __restrict__ scaleOut) {
    int e = blockIdx.x;
    int tid = threadIdx.x, lane = tid & 63, wid = tid >> 6;
    if (e == 0 && tid < 8) scaleOut[tid] = expf(fminf(ls[tid], 4.6051701859880914f));
    int dh = e / 15 - 7, dw = e % 15 - 7;
    float t0 = sgnlog(8.f * (float)dh / 7.f);
    float t1 = sgnlog(8.f * (float)dw / 7.f);
    float acc[8];
#pragma unroll
    for (int j = 0; j < 8; ++j) acc[j] = 0.f;
#pragma unroll
    for (int s = 0; s < 2; ++s) {
        int hsm = tid + s * 256;
        float hid = fmaxf(0.f, t0 * w1[hsm] + t1 * w1[512 + hsm] + b1[hsm]);
#pragma unroll
        for (int j = 0; j < 8; ++j) acc[j] += hid * w2[hsm * 8 + j];
    }
#pragma unroll
    for (int off = 1; off < 64; off <<= 1)
#pragma unroll
        for (int j = 0; j < 8; ++j) acc[j] += __shfl_xor(acc[j], off, 64);
    __shared__ float red[4][8];
    if (lane == 0)
#pragma unroll
        for (int j = 0; j < 8; ++j) red[wid][j] = acc[j];
    __syncthreads();
    if (tid < 8)
        b225g[e * 8 + tid] = red[0][tid] + red[1][tid] + red[2][tid] + red[3][tid];
}

// ---------------- K0c: expand to per-head 64x64 bias ----------------
__global__ __launch_bounds__(256) void bias_expand(const float* __restrict__ b225g,
                                                   float* __restrict__ bias8) {
    int f = blockIdx.x * 256 + threadIdx.x;
    int h = f >> 12, ij = f & 4095, i = ij >> 6, j = ij & 63;
    int dh = (i >> 3) - (j >> 3), dw = (i & 7) - (j & 7);
    int e = (dh + 7) * 15 + (dw + 7);
    float v = b225g[e * 8 + h];
    bias8[f] = 16.f / (1.f + expf(-v));
}

// token row -> pixel (roll by +4 both ways, same map fwd/bwd)
__device__ __forceinline__ int row2pix(int row) {
    int w = row >> 6, t = row & 63;
    int b = w >> 6, wi = (w >> 3) & 7, wj = w & 7;
    int hh = (wi * 8 + (t >> 3) + 4) & 63;
    int ww = (wj * 8 + (t & 7) + 4) & 63;
    return (b * 64 + hh) * 64 + ww;
}

// ---------------- K1: QKV projection (C^T formulation) ----------------
// Block = 1 window (64 tokens), grid 1024, LDS 33.8KB -> 4 blocks/CU.
// Each wave: per t (3 iters) computes 64 n-cols x 64 tokens, acc rows = n (d-contiguous),
// acc cols = tok -> shortx4 vectorized stores into qkv2 layout
// [win][h][q|k|v][tok 64][d 32] (2048 shorts per (win,h,qi) slab) -- unchanged.
__global__ __launch_bounds__(256, 4) void qkv_gemm(const float* __restrict__ x,
                                                   const short* __restrict__ wf,
                                                   const float* __restrict__ bq,
                                                   const float* __restrict__ bk_,
                                                   const float* __restrict__ bv,
                                                   short* __restrict__ qkv2) {
    __shared__ __align__(16) short As[64 * 264];
    int tid = threadIdx.x, lane = tid & 63, wid = tid >> 6;
    int quad = lane >> 4, l15 = lane & 15;
    int win = blockIdx.x;

    // ---- stage A once: 64 rows x 256 k, fp32 gather -> bf16 LDS ----
    {
        int r = tid >> 2, q = tid & 3;
        const float* src = x + (size_t)row2pix(win * 64 + r) * 256 + q * 64;
        short* dst = &As[r * 264 + q * 64];
#pragma unroll
        for (int g = 0; g < 2; ++g) {
            float4 v[8];
#pragma unroll
            for (int j = 0; j < 8; ++j) v[j] = *(const float4*)(src + g * 32 + j * 4);
#pragma unroll
            for (int j = 0; j < 4; ++j) {
                shortx8 s;
#pragma unroll
                for (int q2 = 0; q2 < 2; ++q2) {
                    float4 f = v[j * 2 + q2];
                    s[q2 * 4 + 0] = f2bf(f.x); s[q2 * 4 + 1] = f2bf(f.y);
                    s[q2 * 4 + 2] = f2bf(f.z); s[q2 * 4 + 3] = f2bf(f.w);
                }
                *(shortx8*)(dst + g * 32 + j * 8) = s;
            }
        }
    }

    const short* wbase = wf + lane * 8;

    __syncthreads();  // the only barrier

    for (int t = 0; t < 3; ++t) {
        int n16b = t * 16 + wid * 4;  // wave's n16 base this iteration
        floatx4 acc[4][4];            // [nt][mt]
#pragma unroll
        for (int nt = 0; nt < 4; ++nt)
#pragma unroll
            for (int mt = 0; mt < 4; ++mt) acc[nt][mt] = (floatx4){0.f, 0.f, 0.f, 0.f};
#pragma unroll
        for (int kt = 0; kt < 8; ++kt) {
            shortx8 bw[4], af[4];
#pragma unroll
            for (int nt = 0; nt < 4; ++nt)
                bw[nt] = *(const shortx8*)(wbase + ((size_t)(n16b + nt) * 8 + kt) * 512);
#pragma unroll
            for (int mt = 0; mt < 4; ++mt)
                af[mt] = *(const shortx8*)&As[(mt * 16 + l15) * 264 + kt * 32 + quad * 8];
#pragma unroll
            for (int nt = 0; nt < 4; ++nt)
#pragma unroll
                for (int mt = 0; mt < 4; ++mt)
                    acc[nt][mt] = __builtin_amdgcn_mfma_f32_16x16x32_bf16(bw[nt], af[mt], acc[nt][mt], 0, 0, 0);
        }
        // epilogue: C^T tile -> rows = n (d-contiguous per thread), cols = tok
#pragma unroll
        for (int nt = 0; nt < 4; ++nt) {
            int nb = (n16b + nt) * 16;            // multiple of 16
            int qi = nb >> 8, h = (nb >> 5) & 7;
            int db = (nb & 31) + quad * 4;
            size_t slab = (size_t)win * 49152 + (size_t)(h * 3 + qi) * 2048;
            float bs[4];
#pragma unroll
            for (int reg = 0; reg < 4; ++reg) {
                int n = nb + quad * 4 + reg;
                bs[reg] = (n < 256) ? bq[n] : (n < 512) ? bk_[n - 256] : bv[n - 512];
            }
#pragma unroll
            for (int mt = 0; mt < 4; ++mt) {
                int tok = mt * 16 + l15;
                shortx4 s;
#pragma unroll
                for (int reg = 0; reg < 4; ++reg) s[reg] = f2bf(acc[nt][mt][reg] + bs[reg]);
                *(shortx4*)(qkv2 + slab + tok * 32 + db) = s;
            }
        }
    }
}

// ---------------- K3: per-window attention (wave-private LDS, no barriers) ----------------
__device__ __forceinline__ int regid(int t, int wi, int wj) {
    int a = (wi < 7) ? 0 : (((t >> 3) < 4) ? 1 : 2);
    int b = (wj < 7) ? 0 : (((t & 7) < 4) ? 1 : 2);
    return a * 3 + b;
}

__global__ __launch_bounds__(256, 2) void attn_kernel(const short* __restrict__ qkv2,
                                                      const float* __restrict__ bias8,
                                                      const float* __restrict__ scale,
                                                      short* __restrict__ aout) {
    __shared__ __align__(16) short lds[4 * 8192];
    int tid = threadIdx.x, lane = tid & 63, wid = tid >> 6;
    int quad = lane >> 4, l15 = lane & 15;
    int win = blockIdx.x;
    int wi = (win >> 3) & 7, wj = win & 7;
    bool need_mask = (wi == 7) || (wj == 7);
    short* qn = &lds[wid * 8192];
    short* kn = qn + 3584;
    short* P = qn;
    short* vt = qn + 5632;

    for (int hi = 0; hi < 2; ++hi) {
        int h = wid + hi * 4;
        float sc = scale[h];
        const short* base = qkv2 + (size_t)(win * 8 + h) * 3 * 2048;
        shortx8 qraw[4], kraw[4], vraw[4];
#pragma unroll
        for (int c2 = 0; c2 < 4; ++c2) {
            qraw[c2] = *(const shortx8*)(base + lane * 32 + c2 * 8);
            kraw[c2] = *(const shortx8*)(base + 2048 + lane * 32 + c2 * 8);
            vraw[c2] = *(const shortx8*)(base + 4096 + lane * 32 + c2 * 8);
        }
        float qs = 0.f, ks2 = 0.f;
#pragma unroll
        for (int c2 = 0; c2 < 4; ++c2)
#pragma unroll
            for (int j = 0; j < 8; ++j) {
                float f = bf2f(qraw[c2][j]); qs += f * f;
                float g = bf2f(kraw[c2][j]); ks2 += g * g;
            }
        float qr = sc / fmaxf(sqrtf(qs), 1e-12f);
        float kr = 1.f / fmaxf(sqrtf(ks2), 1e-12f);
        CFENCE();
#pragma unroll
        for (int c2 = 0; c2 < 4; ++c2) {
            shortx8 oq, ok;
#pragma unroll
            for (int j = 0; j < 8; ++j) {
                oq[j] = f2bf(bf2f(qraw[c2][j]) * qr);
                ok[j] = f2bf(bf2f(kraw[c2][j]) * kr);
            }
            *(shortx8*)&qn[lane * 56 + c2 * 8] = oq;
            *(shortx8*)&kn[lane * 56 + c2 * 8] = ok;
        }
        CFENCE();
        shortx8 aq[4], bkf[4];
#pragma unroll
        for (int mt = 0; mt < 4; ++mt)
            aq[mt] = *(const shortx8*)&qn[(mt * 16 + l15) * 56 + quad * 8];
#pragma unroll
        for (int nt = 0; nt < 4; ++nt)
            bkf[nt] = *(const shortx8*)&kn[(nt * 16 + l15) * 56 + quad * 8];
        floatx4 S[4][4];
#pragma unroll
        for (int mt = 0; mt < 4; ++mt)
#pragma unroll
            for (int nt = 0; nt < 4; ++nt) {
                floatx4 z = {0.f, 0.f, 0.f, 0.f};
                S[mt][nt] = __builtin_amdgcn_mfma_f32_16x16x32_bf16(aq[mt], bkf[nt], z, 0, 0, 0);
            }
        const float* bh = bias8 + (h << 12);
        float bound = sc + 16.5f;
        int jid[4];
        if (need_mask) {
#pragma unroll
            for (int nt = 0; nt < 4; ++nt) jid[nt] = regid(nt * 16 + l15, wi, wj);
        }
        float rs[4][4];
#pragma unroll
        for (int mt = 0; mt < 4; ++mt)
#pragma unroll
            for (int reg = 0; reg < 4; ++reg) {
                int i = mt * 16 + quad * 4 + reg;
                int iid = need_mask ? regid(i, wi, wj) : 0;
                float rowsum = 0.f;
#pragma unroll
                for (int nt = 0; nt < 4; ++nt) {
                    int j = nt * 16 + l15;
                    float v = S[mt][nt][reg] + bh[i * 64 + j];
                    if (need_mask && iid != jid[nt]) v -= 100.f;
                    float p = __expf(v - bound);
                    S[mt][nt][reg] = p;
                    rowsum += p;
                }
                rowsum += __shfl_xor(rowsum, 1, 64);
                rowsum += __shfl_xor(rowsum, 2, 64);
                rowsum += __shfl_xor(rowsum, 4, 64);
                rowsum += __shfl_xor(rowsum, 8, 64);
                rs[mt][reg] = 1.f / rowsum;
            }
        CFENCE();
#pragma unroll
        for (int mt = 0; mt < 4; ++mt)
#pragma unroll
            for (int nt = 0; nt < 4; ++nt)
#pragma unroll
                for (int reg = 0; reg < 4; ++reg)
                    P[(mt * 16 + quad * 4 + reg) * 88 + nt * 16 + l15] = f2bf(S[mt][nt][reg]);
#pragma unroll
        for (int c2 = 0; c2 < 4; ++c2)
#pragma unroll
            for (int j = 0; j < 8; ++j)
                vt[(c2 * 8 + j) * 72 + lane] = vraw[c2][j];
        CFENCE();
        floatx4 O[4][2];
#pragma unroll
        for (int mt = 0; mt < 4; ++mt)
#pragma unroll
            for (int nt = 0; nt < 2; ++nt) O[mt][nt] = (floatx4){0.f, 0.f, 0.f, 0.f};
#pragma unroll
        for (int ks = 0; ks < 2; ++ks) {
            shortx8 pa[4], vb[2];
#pragma unroll
            for (int mt = 0; mt < 4; ++mt)
                pa[mt] = *(const shortx8*)&P[(mt * 16 + l15) * 88 + ks * 32 + quad * 8];
#pragma unroll
            for (int nt = 0; nt < 2; ++nt)
                vb[nt] = *(const shortx8*)&vt[(nt * 16 + l15) * 72 + ks * 32 + quad * 8];
#pragma unroll
            for (int mt = 0; mt < 4; ++mt)
#pragma unroll
                for (int nt = 0; nt < 2; ++nt)
                    O[mt][nt] = __builtin_amdgcn_mfma_f32_16x16x32_bf16(pa[mt], vb[nt], O[mt][nt], 0, 0, 0);
        }
#pragma unroll
        for (int mt = 0; mt < 4; ++mt)
#pragma unroll
            for (int nt = 0; nt < 2; ++nt)
#pragma unroll
                for (int reg = 0; reg < 4; ++reg) {
                    int i = mt * 16 + quad * 4 + reg;
                    int d = nt * 16 + l15;
                    aout[(size_t)(win * 64 + i) * 256 + (h << 5) + d] =
                        f2bf(O[mt][nt][reg] * rs[mt][reg]);
                }
    }
}

// ---------------- K4: output projection (C^T formulation) ----------------
// Block = 64 rows, grid 1024, LDS 33.8KB -> 4 blocks/CU. Single n-pass (4 waves x 64 = 256).
// acc rows = out-channel (contiguous per thread) -> float4 stores.
__global__ __launch_bounds__(256, 4) void oproj_gemm(const short* __restrict__ ao,
                                                     const short* __restrict__ wof,
                                                     const float* __restrict__ bo,
                                                     float* __restrict__ out) {
    __shared__ __align__(16) short As[64 * 264];
    int tid = threadIdx.x, lane = tid & 63, wid = tid >> 6;
    int quad = lane >> 4, l15 = lane & 15;
    int bm = blockIdx.x;

    {
        int r = tid >> 2, q = tid & 3;
        const short* src = ao + (size_t)(bm * 64 + r) * 256 + q * 64;
        short* dst = &As[r * 264 + q * 64];
#pragma unroll
        for (int j = 0; j < 8; ++j)
            *(shortx8*)(dst + j * 8) = *(const shortx8*)(src + j * 8);
    }

    const short* wbase = wof + lane * 8;

    __syncthreads();

    floatx4 acc[4][4];  // [nt][mt]
#pragma unroll
    for (int nt = 0; nt < 4; ++nt)
#pragma unroll
        for (int mt = 0; mt < 4; ++mt) acc[nt][mt] = (floatx4){0.f, 0.f, 0.f, 0.f};
#pragma unroll
    for (int kt = 0; kt < 8; ++kt) {
        shortx8 bw[4], af[4];
#pragma unroll
        for (int nt = 0; nt < 4; ++nt)
            bw[nt] = *(const shortx8*)(wbase + ((size_t)(wid * 4 + nt) * 8 + kt) * 512);
#pragma unroll
        for (int mt = 0; mt < 4; ++mt)
            af[mt] = *(const shortx8*)&As[(mt * 16 + l15) * 264 + kt * 32 + quad * 8];
#pragma unroll
        for (int nt = 0; nt < 4; ++nt)
#pragma unroll
            for (int mt = 0; mt < 4; ++mt)
                acc[nt][mt] = __builtin_amdgcn_mfma_f32_16x16x32_bf16(bw[nt], af[mt], acc[nt][mt], 0, 0, 0);
    }

    int pix[4];
#pragma unroll
    for (int mt = 0; mt < 4; ++mt) pix[mt] = row2pix(bm * 64 + mt * 16 + l15);
#pragma unroll
    for (int nt = 0; nt < 4; ++nt) {
        int nb = wid * 64 + nt * 16 + quad * 4;
        float bs[4];
#pragma unroll
        for (int reg = 0; reg < 4; ++reg) bs[reg] = bo[nb + reg];
#pragma unroll
        for (int mt = 0; mt < 4; ++mt) {
            float4 o;
            o.x = acc[nt][mt][0] + bs[0];
            o.y = acc[nt][mt][1] + bs[1];
            o.z = acc[nt][mt][2] + bs[2];
            o.w = acc[nt][mt][3] + bs[3];
            *(float4*)(out + (size_t)pix[mt] * 256 + nb) = o;
        }
    }
}

// ---------------- launch ----------------
extern "C" void kernel_launch(void* const* d_in, const int* in_sizes, int n_in,
                              void* d_out, int out_size, void* d_ws, size_t ws_size,
                              hipStream_t stream) {
    const float* x  = (const float*)d_in[0];
    const float* Wq = (const float*)d_in[1];
    const float* bq = (const float*)d_in[2];
    const float* Wk = (const float*)d_in[3];
    const float* bk = (const float*)d_in[4];
    const float* Wv = (const float*)d_in[5];
    const float* bv = (const float*)d_in[6];
    const float* Wo = (const float*)d_in[7];
    const float* bo = (const float*)d_in[8];
    const float* ls = (const float*)d_in[9];
    const float* w1 = (const float*)d_in[10];
    const float* b1 = (const float*)d_in[11];
    const float* w2 = (const float*)d_in[12];

    char* ws = (char*)d_ws;
    short* wqkv_f = (short*)(ws + 0);           //   393,216 B
    short* wo_f   = (short*)(ws + 393216);      //   131,072 B
    float* bias8  = (float*)(ws + 524288);      //   131,072 B
    float* scale  = (float*)(ws + 655360);      //        32 B
    float* b225g  = (float*)(ws + 786432);      //     7,200 B
    short* qkv2   = (short*)(ws + 1048576);     // 100,663,296 B
    short* aout   = (short*)(ws + 101711872);   //  33,554,432 B
    float* out    = (float*)d_out;

    hipLaunchKernelGGL(wtrans, dim3(128), dim3(256), 0, stream, Wq, Wk, Wv, Wo, wqkv_f, wo_f);
    hipLaunchKernelGGL(bias_mlp, dim3(225), dim3(256), 0, stream, ls, w1, b1, w2, b225g, scale);
    hipLaunchKernelGGL(bias_expand, dim3(128), dim3(256), 0, stream, b225g, bias8);
    hipLaunchKernelGGL(qkv_gemm, dim3(1024), dim3(256), 0, stream, x, wqkv_f, bq, bk, bv, qkv2);
    hipLaunchKernelGGL(attn_kernel, dim3(1024), dim3(256), 0, stream, qkv2, bias8, scale, aout);
    hipLaunchKernelGGL(oproj_gemm, dim3(1024), dim3(256), 0, stream, aout, wo_f, bo, out);
}

// Round 2
// 285.500 us; speedup vs baseline: 1.1454x; 1.1454x over previous
//
#include <hip/hip_runtime.h>
#include <hip/hip_bf16.h>

typedef float floatx4 __attribute__((ext_vector_type(4)));
typedef short shortx8 __attribute__((ext_vector_type(8)));
typedef short shortx4 __attribute__((ext_vector_type(4)));

#define CFENCE() asm volatile("" ::: "memory")

__device__ __forceinline__ float bf2f(short s) {
    union { unsigned u; float f; } cv;
    cv.u = ((unsigned)(unsigned short)s) << 16;
    return cv.f;
}
__device__ __forceinline__ short f2bf(float f) {
    union { float f; unsigned u; } cv; cv.f = f;
    unsigned r = (cv.u + 0x7fffu + ((cv.u >> 16) & 1u)) >> 16;
    return (short)r;
}

// ---------------- K0a: weights -> bf16 fragment-major layout ----------------
// wqkv_f: 384 frags (n16 0..47, kt 0..7), each 64 lanes x 8 shorts contiguous (1KB)
// wo_f:   128 frags (n16 0..15, kt 0..7)
// frag element: B[n = n16*16 + (lane&15)][k = kt*32 + (lane>>4)*8 + j]
__global__ __launch_bounds__(256) void wtrans(const float* __restrict__ Wq,
                                              const float* __restrict__ Wk,
                                              const float* __restrict__ Wv,
                                              const float* __restrict__ Wo,
                                              short* __restrict__ wqkv_f,
                                              short* __restrict__ wo_f) {
    int gtid = blockIdx.x * 256 + threadIdx.x;
    int f = gtid >> 6, lane = gtid & 63;
    int quad = lane >> 4, l15 = lane & 15;
    if (f < 384) {
        int n16 = f >> 3, kt = f & 7;
        int n = n16 * 16 + l15, z = n >> 8, ncol = n & 255;
        const float* src = (z == 0) ? Wq : (z == 1) ? Wk : Wv;
        shortx8 s;
#pragma unroll
        for (int j = 0; j < 8; ++j)
            s[j] = f2bf(src[(size_t)(kt * 32 + quad * 8 + j) * 256 + ncol]);
        *(shortx8*)(wqkv_f + (size_t)f * 512 + lane * 8) = s;
    } else {
        int f2 = f - 384;
        int n16 = f2 >> 3, kt = f2 & 7;
        int n = n16 * 16 + l15;
        shortx8 s;
#pragma unroll
        for (int j = 0; j < 8; ++j)
            s[j] = f2bf(Wo[(size_t)(kt * 32 + quad * 8 + j) * 256 + n]);
        *(shortx8*)(wo_f + (size_t)f2 * 512 + lane * 8) = s;
    }
}

// ---------------- K0b: CPB MLP, one block per table entry ----------------
__device__ __forceinline__ float sgnlog(float x) {
    return copysignf(__log2f(fabsf(x) + 1.f) / 3.f, x);
}
__global__ __launch_bounds__(256) void bias_mlp(const float* __restrict__ ls,
                                                const float* __restrict__ w1,
                                                const float* __restrict__ b1,
                                                const float* __restrict__ w2,
                                                float* __restrict__ b225g,
                                                float* __restrict__ scaleOut) {
    int e = blockIdx.x;
    int tid = threadIdx.x, lane = tid & 63, wid = tid >> 6;
    if (e == 0 && tid < 8) scaleOut[tid] = expf(fminf(ls[tid], 4.6051701859880914f));
    int dh = e / 15 - 7, dw = e % 15 - 7;
    float t0 = sgnlog(8.f * (float)dh / 7.f);
    float t1 = sgnlog(8.f * (float)dw / 7.f);
    float acc[8];
#pragma unroll
    for (int j = 0; j < 8; ++j) acc[j] = 0.f;
#pragma unroll
    for (int s = 0; s < 2; ++s) {
        int hsm = tid + s * 256;
        float hid = fmaxf(0.f, t0 * w1[hsm] + t1 * w1[512 + hsm] + b1[hsm]);
#pragma unroll
        for (int j = 0; j < 8; ++j) acc[j] += hid * w2[hsm * 8 + j];
    }
#pragma unroll
    for (int off = 1; off < 64; off <<= 1)
#pragma unroll
        for (int j = 0; j < 8; ++j) acc[j] += __shfl_xor(acc[j], off, 64);
    __shared__ float red[4][8];
    if (lane == 0)
#pragma unroll
        for (int j = 0; j < 8; ++j) red[wid][j] = acc[j];
    __syncthreads();
    if (tid < 8)
        b225g[e * 8 + tid] = red[0][tid] + red[1][tid] + red[2][tid] + red[3][tid];
}

// ---------------- K0c: expand to per-head 64x64 bias ----------------
__global__ __launch_bounds__(256) void bias_expand(const float* __restrict__ b225g,
                                                   float* __restrict__ bias8) {
    int f = blockIdx.x * 256 + threadIdx.x;
    int h = f >> 12, ij = f & 4095, i = ij >> 6, j = ij & 63;
    int dh = (i >> 3) - (j >> 3), dw = (i & 7) - (j & 7);
    int e = (dh + 7) * 15 + (dw + 7);
    float v = b225g[e * 8 + h];
    bias8[f] = 16.f / (1.f + expf(-v));
}

// token row -> pixel (roll by +4 both ways, same map fwd/bwd)
__device__ __forceinline__ int row2pix(int row) {
    int w = row >> 6, t = row & 63;
    int b = w >> 6, wi = (w >> 3) & 7, wj = w & 7;
    int hh = (wi * 8 + (t >> 3) + 4) & 63;
    int ww = (wj * 8 + (t & 7) + 4) & 63;
    return (b * 64 + hh) * 64 + ww;
}

__device__ __forceinline__ int regid(int t, int wi, int wj) {
    int a = (wi < 7) ? 0 : (((t >> 3) < 4) ? 1 : 2);
    int b = (wj < 7) ? 0 : (((t & 7) < 4) ? 1 : 2);
    return a * 3 + b;
}

// ---------------- Fused: QKV gemm + attention + O-proj, one block per window ----------------
// 4 waves; wave w handles heads 2w (pass 0) and 2w+1 (pass 1).
// QKV in C^T form: acc = mfma(weight_frag, token_frag) -> rows=n(channel), cols=token.
// Wave-private LDS scratch per pass: qn[64][40], kn[64][40], vt[32][72], P[64][72] (aliases qn/kn).
// After both passes: shared Ao[64][264] bf16 tile -> O-proj C^T -> float4 scatter to out.
__global__ __launch_bounds__(256, 2) void swin_fused(const float* __restrict__ x,
                                                     const short* __restrict__ wf,
                                                     const short* __restrict__ wof,
                                                     const float* __restrict__ bq,
                                                     const float* __restrict__ bk_,
                                                     const float* __restrict__ bv,
                                                     const float* __restrict__ bo,
                                                     const float* __restrict__ bias8,
                                                     const float* __restrict__ scale,
                                                     float* __restrict__ out) {
    __shared__ __align__(16) short lds[4 * 8192];   // 64 KB
    int tid = threadIdx.x, lane = tid & 63, wid = tid >> 6;
    int quad = lane >> 4, l15 = lane & 15;
    int win = blockIdx.x;
    int wi = (win >> 3) & 7, wj = win & 7;
    bool need_mask = (wi == 7) || (wj == 7);

    short* qn = &lds[wid * 8192];        // [64][40]  (2560)
    short* kn = qn + 2560;               // [64][40]  (2560)
    short* vt = qn + 5120;               // [32][72]  (2304)
    short* P  = qn;                      // [64][72]  (4608) aliases qn+kn after frags read

    int pix[4];
#pragma unroll
    for (int mt = 0; mt < 4; ++mt) pix[mt] = row2pix(win * 64 + mt * 16 + l15);

    float Of[2][4][2][4];                // per-pass scaled attn output (regs)

#pragma unroll
    for (int p = 0; p < 2; ++p) {
        int h = wid * 2 + p;
        // ---- QKV GEMM (C^T): 24 MFMA per kt ----
        floatx4 aq[2][4], ak[2][4], av[2][4];
#pragma unroll
        for (int i = 0; i < 2; ++i)
#pragma unroll
            for (int mt = 0; mt < 4; ++mt) {
                aq[i][mt] = (floatx4){0.f, 0.f, 0.f, 0.f};
                ak[i][mt] = (floatx4){0.f, 0.f, 0.f, 0.f};
                av[i][mt] = (floatx4){0.f, 0.f, 0.f, 0.f};
            }
#pragma unroll
        for (int kt = 0; kt < 8; ++kt) {
            shortx8 af[4];
#pragma unroll
            for (int mt = 0; mt < 4; ++mt) {
                const float* s = x + (size_t)pix[mt] * 256 + kt * 32 + quad * 8;
                float4 u0 = *(const float4*)s;
                float4 u1 = *(const float4*)(s + 4);
                shortx8 t;
                t[0] = f2bf(u0.x); t[1] = f2bf(u0.y); t[2] = f2bf(u0.z); t[3] = f2bf(u0.w);
                t[4] = f2bf(u1.x); t[5] = f2bf(u1.y); t[6] = f2bf(u1.z); t[7] = f2bf(u1.w);
                af[mt] = t;
            }
            shortx8 wqf[2], wkf[2], wvf[2];
#pragma unroll
            for (int i = 0; i < 2; ++i) {
                int n16 = 2 * h + i;
                wqf[i] = *(const shortx8*)(wf + (size_t)((n16)*8 + kt) * 512 + lane * 8);
                wkf[i] = *(const shortx8*)(wf + (size_t)((16 + n16) * 8 + kt) * 512 + lane * 8);
                wvf[i] = *(const shortx8*)(wf + (size_t)((32 + n16) * 8 + kt) * 512 + lane * 8);
            }
#pragma unroll
            for (int i = 0; i < 2; ++i)
#pragma unroll
                for (int mt = 0; mt < 4; ++mt) {
                    aq[i][mt] = __builtin_amdgcn_mfma_f32_16x16x32_bf16(wqf[i], af[mt], aq[i][mt], 0, 0, 0);
                    ak[i][mt] = __builtin_amdgcn_mfma_f32_16x16x32_bf16(wkf[i], af[mt], ak[i][mt], 0, 0, 0);
                    av[i][mt] = __builtin_amdgcn_mfma_f32_16x16x32_bf16(wvf[i], af[mt], av[i][mt], 0, 0, 0);
                }
        }
        // ---- bias + cosine norms (token = col = l15-group; sum over quads via shfl) ----
        float sc = scale[h];
        float qs[4], ks[4];
#pragma unroll
        for (int mt = 0; mt < 4; ++mt) { qs[mt] = 0.f; ks[mt] = 0.f; }
#pragma unroll
        for (int i = 0; i < 2; ++i) {
            float bqv[4], bkv[4], bvv[4];
#pragma unroll
            for (int r = 0; r < 4; ++r) {
                int d = i * 16 + quad * 4 + r;
                bqv[r] = bq[h * 32 + d];
                bkv[r] = bk_[h * 32 + d];
                bvv[r] = bv[h * 32 + d];
            }
#pragma unroll
            for (int mt = 0; mt < 4; ++mt)
#pragma unroll
                for (int r = 0; r < 4; ++r) {
                    float qv = aq[i][mt][r] + bqv[r]; aq[i][mt][r] = qv; qs[mt] += qv * qv;
                    float kv = ak[i][mt][r] + bkv[r]; ak[i][mt][r] = kv; ks[mt] += kv * kv;
                    av[i][mt][r] += bvv[r];
                }
        }
#pragma unroll
        for (int mt = 0; mt < 4; ++mt) {
            qs[mt] += __shfl_xor(qs[mt], 16, 64); qs[mt] += __shfl_xor(qs[mt], 32, 64);
            ks[mt] += __shfl_xor(ks[mt], 16, 64); ks[mt] += __shfl_xor(ks[mt], 32, 64);
        }
        CFENCE();
        // ---- write normalized q,k and transposed v into wave-private LDS ----
#pragma unroll
        for (int mt = 0; mt < 4; ++mt) {
            float qr = sc / fmaxf(sqrtf(qs[mt]), 1e-12f);
            float kr = 1.f / fmaxf(sqrtf(ks[mt]), 1e-12f);
            int tok = mt * 16 + l15;
#pragma unroll
            for (int i = 0; i < 2; ++i) {
                shortx4 oq, ok;
#pragma unroll
                for (int r = 0; r < 4; ++r) {
                    oq[r] = f2bf(aq[i][mt][r] * qr);
                    ok[r] = f2bf(ak[i][mt][r] * kr);
                }
                *(shortx4*)&qn[tok * 40 + i * 16 + quad * 4] = oq;
                *(shortx4*)&kn[tok * 40 + i * 16 + quad * 4] = ok;
#pragma unroll
                for (int r = 0; r < 4; ++r)
                    vt[(i * 16 + quad * 4 + r) * 72 + tok] = f2bf(av[i][mt][r]);
            }
        }
        CFENCE();
        // ---- QK^T ----
        shortx8 aqf[4], bkf[4];
#pragma unroll
        for (int mt = 0; mt < 4; ++mt)
            aqf[mt] = *(const shortx8*)&qn[(mt * 16 + l15) * 40 + quad * 8];
#pragma unroll
        for (int nt = 0; nt < 4; ++nt)
            bkf[nt] = *(const shortx8*)&kn[(nt * 16 + l15) * 40 + quad * 8];
        floatx4 S[4][4];
#pragma unroll
        for (int mt = 0; mt < 4; ++mt)
#pragma unroll
            for (int nt = 0; nt < 4; ++nt) {
                floatx4 z = {0.f, 0.f, 0.f, 0.f};
                S[mt][nt] = __builtin_amdgcn_mfma_f32_16x16x32_bf16(aqf[mt], bkf[nt], z, 0, 0, 0);
            }
        // ---- softmax ----
        const float* bh = bias8 + (h << 12);
        float bound = sc + 16.5f;
        int jid[4];
        if (need_mask) {
#pragma unroll
            for (int nt = 0; nt < 4; ++nt) jid[nt] = regid(nt * 16 + l15, wi, wj);
        }
        float rs[4][4];
#pragma unroll
        for (int mt = 0; mt < 4; ++mt)
#pragma unroll
            for (int reg = 0; reg < 4; ++reg) {
                int i = mt * 16 + quad * 4 + reg;
                int iid = need_mask ? regid(i, wi, wj) : 0;
                float rowsum = 0.f;
#pragma unroll
                for (int nt = 0; nt < 4; ++nt) {
                    int j = nt * 16 + l15;
                    float v = S[mt][nt][reg] + bh[i * 64 + j];
                    if (need_mask && iid != jid[nt]) v -= 100.f;
                    float pe = __expf(v - bound);
                    S[mt][nt][reg] = pe;
                    rowsum += pe;
                }
                rowsum += __shfl_xor(rowsum, 1, 64);
                rowsum += __shfl_xor(rowsum, 2, 64);
                rowsum += __shfl_xor(rowsum, 4, 64);
                rowsum += __shfl_xor(rowsum, 8, 64);
                rs[mt][reg] = 1.f / rowsum;
            }
        CFENCE();
        // ---- P to LDS (aliases qn/kn; frags already consumed) ----
#pragma unroll
        for (int mt = 0; mt < 4; ++mt)
#pragma unroll
            for (int nt = 0; nt < 4; ++nt)
#pragma unroll
                for (int reg = 0; reg < 4; ++reg)
                    P[(mt * 16 + quad * 4 + reg) * 72 + nt * 16 + l15] = f2bf(S[mt][nt][reg]);
        CFENCE();
        // ---- PV ----
        floatx4 O[4][2];
#pragma unroll
        for (int mt = 0; mt < 4; ++mt)
#pragma unroll
            for (int nt = 0; nt < 2; ++nt) O[mt][nt] = (floatx4){0.f, 0.f, 0.f, 0.f};
#pragma unroll
        for (int ks2 = 0; ks2 < 2; ++ks2) {
            shortx8 pa[4], vb[2];
#pragma unroll
            for (int mt = 0; mt < 4; ++mt)
                pa[mt] = *(const shortx8*)&P[(mt * 16 + l15) * 72 + ks2 * 32 + quad * 8];
#pragma unroll
            for (int nt = 0; nt < 2; ++nt)
                vb[nt] = *(const shortx8*)&vt[(nt * 16 + l15) * 72 + ks2 * 32 + quad * 8];
#pragma unroll
            for (int mt = 0; mt < 4; ++mt)
#pragma unroll
                for (int nt = 0; nt < 2; ++nt)
                    O[mt][nt] = __builtin_amdgcn_mfma_f32_16x16x32_bf16(pa[mt], vb[nt], O[mt][nt], 0, 0, 0);
        }
#pragma unroll
        for (int mt = 0; mt < 4; ++mt)
#pragma unroll
            for (int nt = 0; nt < 2; ++nt)
#pragma unroll
                for (int reg = 0; reg < 4; ++reg)
                    Of[p][mt][nt][reg] = O[mt][nt][reg] * rs[mt][reg];
        CFENCE();
    }

    // ---- gather attn outputs into shared Ao[64][264], then O-proj ----
    __syncthreads();
    short* Ao = lds;
#pragma unroll
    for (int p = 0; p < 2; ++p) {
        int h = wid * 2 + p;
#pragma unroll
        for (int mt = 0; mt < 4; ++mt)
#pragma unroll
            for (int nt = 0; nt < 2; ++nt)
#pragma unroll
                for (int reg = 0; reg < 4; ++reg)
                    Ao[(mt * 16 + quad * 4 + reg) * 264 + h * 32 + nt * 16 + l15] =
                        f2bf(Of[p][mt][nt][reg]);
    }
    __syncthreads();

    floatx4 acc2[4][4];   // [nt][mt]
#pragma unroll
    for (int nt = 0; nt < 4; ++nt)
#pragma unroll
        for (int mt = 0; mt < 4; ++mt) acc2[nt][mt] = (floatx4){0.f, 0.f, 0.f, 0.f};
#pragma unroll
    for (int kt = 0; kt < 8; ++kt) {
        shortx8 bw[4], af2[4];
#pragma unroll
        for (int nt = 0; nt < 4; ++nt)
            bw[nt] = *(const shortx8*)(wof + (size_t)((wid * 4 + nt) * 8 + kt) * 512 + lane * 8);
#pragma unroll
        for (int mt = 0; mt < 4; ++mt)
            af2[mt] = *(const shortx8*)&Ao[(mt * 16 + l15) * 264 + kt * 32 + quad * 8];
#pragma unroll
        for (int nt = 0; nt < 4; ++nt)
#pragma unroll
            for (int mt = 0; mt < 4; ++mt)
                acc2[nt][mt] = __builtin_amdgcn_mfma_f32_16x16x32_bf16(bw[nt], af2[mt], acc2[nt][mt], 0, 0, 0);
    }
#pragma unroll
    for (int nt = 0; nt < 4; ++nt) {
        int nb = wid * 64 + nt * 16 + quad * 4;
        float bs[4];
#pragma unroll
        for (int reg = 0; reg < 4; ++reg) bs[reg] = bo[nb + reg];
#pragma unroll
        for (int mt = 0; mt < 4; ++mt) {
            float4 o;
            o.x = acc2[nt][mt][0] + bs[0];
            o.y = acc2[nt][mt][1] + bs[1];
            o.z = acc2[nt][mt][2] + bs[2];
            o.w = acc2[nt][mt][3] + bs[3];
            *(float4*)(out + (size_t)pix[mt] * 256 + nb) = o;
        }
    }
}

// ---------------- launch ----------------
extern "C" void kernel_launch(void* const* d_in, const int* in_sizes, int n_in,
                              void* d_out, int out_size, void* d_ws, size_t ws_size,
                              hipStream_t stream) {
    const float* x  = (const float*)d_in[0];
    const float* Wq = (const float*)d_in[1];
    const float* bq = (const float*)d_in[2];
    const float* Wk = (const float*)d_in[3];
    const float* bk = (const float*)d_in[4];
    const float* Wv = (const float*)d_in[5];
    const float* bv = (const float*)d_in[6];
    const float* Wo = (const float*)d_in[7];
    const float* bo = (const float*)d_in[8];
    const float* ls = (const float*)d_in[9];
    const float* w1 = (const float*)d_in[10];
    const float* b1 = (const float*)d_in[11];
    const float* w2 = (const float*)d_in[12];

    char* ws = (char*)d_ws;
    short* wqkv_f = (short*)(ws + 0);           //   393,216 B
    short* wo_f   = (short*)(ws + 393216);      //   131,072 B
    float* bias8  = (float*)(ws + 524288);      //   131,072 B
    float* scale  = (float*)(ws + 655360);      //        32 B
    float* b225g  = (float*)(ws + 786432);      //     7,200 B
    float* out    = (float*)d_out;

    hipLaunchKernelGGL(wtrans, dim3(128), dim3(256), 0, stream, Wq, Wk, Wv, Wo, wqkv_f, wo_f);
    hipLaunchKernelGGL(bias_mlp, dim3(225), dim3(256), 0, stream, ls, w1, b1, w2, b225g, scale);
    hipLaunchKernelGGL(bias_expand, dim3(128), dim3(256), 0, stream, b225g, bias8);
    hipLaunchKernelGGL(swin_fused, dim3(1024), dim3(256), 0, stream,
                       x, wqkv_f, wo_f, bq, bk, bv, bo, bias8, scale, out);
}

// Round 3
// 238.169 us; speedup vs baseline: 1.3730x; 1.1987x over previous
//
#include <hip/hip_runtime.h>
#include <hip/hip_bf16.h>

typedef float floatx4 __attribute__((ext_vector_type(4)));
typedef short shortx8 __attribute__((ext_vector_type(8)));
typedef short shortx4 __attribute__((ext_vector_type(4)));

#define CFENCE() asm volatile("" ::: "memory")

__device__ __forceinline__ float bf2f(short s) {
    union { unsigned u; float f; } cv;
    cv.u = ((unsigned)(unsigned short)s) << 16;
    return cv.f;
}
__device__ __forceinline__ short f2bf(float f) {
    union { float f; unsigned u; } cv; cv.f = f;
    unsigned r = (cv.u + 0x7fffu + ((cv.u >> 16) & 1u)) >> 16;
    return (short)r;
}

// ---------------- K0a: weights -> bf16 fragment-major layout ----------------
// wqkv_f: 384 frags (n16 0..47, kt 0..7), each 64 lanes x 8 shorts contiguous (1KB)
// wo_f:   128 frags (n16 0..15, kt 0..7)
// frag element: B[n = n16*16 + (lane&15)][k = kt*32 + (lane>>4)*8 + j]
__global__ __launch_bounds__(256) void wtrans(const float* __restrict__ Wq,
                                              const float* __restrict__ Wk,
                                              const float* __restrict__ Wv,
                                              const float* __restrict__ Wo,
                                              short* __restrict__ wqkv_f,
                                              short* __restrict__ wo_f) {
    int gtid = blockIdx.x * 256 + threadIdx.x;
    int f = gtid >> 6, lane = gtid & 63;
    int quad = lane >> 4, l15 = lane & 15;
    if (f < 384) {
        int n16 = f >> 3, kt = f & 7;
        int n = n16 * 16 + l15, z = n >> 8, ncol = n & 255;
        const float* src = (z == 0) ? Wq : (z == 1) ? Wk : Wv;
        shortx8 s;
#pragma unroll
        for (int j = 0; j < 8; ++j)
            s[j] = f2bf(src[(size_t)(kt * 32 + quad * 8 + j) * 256 + ncol]);
        *(shortx8*)(wqkv_f + (size_t)f * 512 + lane * 8) = s;
    } else {
        int f2 = f - 384;
        int n16 = f2 >> 3, kt = f2 & 7;
        int n = n16 * 16 + l15;
        shortx8 s;
#pragma unroll
        for (int j = 0; j < 8; ++j)
            s[j] = f2bf(Wo[(size_t)(kt * 32 + quad * 8 + j) * 256 + n]);
        *(shortx8*)(wo_f + (size_t)f2 * 512 + lane * 8) = s;
    }
}

// ---------------- K0b: CPB MLP, one block per table entry ----------------
__device__ __forceinline__ float sgnlog(float x) {
    return copysignf(__log2f(fabsf(x) + 1.f) / 3.f, x);
}
__global__ __launch_bounds__(256) void bias_mlp(const float* __restrict__ ls,
                                                const float* __restrict__ w1,
                                                const float* __restrict__ b1,
                                                const float* __restrict__ w2,
                                                float* __restrict__ b225g,
                                                float* __restrict__ scaleOut) {
    int e = blockIdx.x;
    int tid = threadIdx.x, lane = tid & 63, wid = tid >> 6;
    if (e == 0 && tid < 8) scaleOut[tid] = expf(fminf(ls[tid], 4.6051701859880914f));
    int dh = e / 15 - 7, dw = e % 15 - 7;
    float t0 = sgnlog(8.f * (float)dh / 7.f);
    float t1 = sgnlog(8.f * (float)dw / 7.f);
    float acc[8];
#pragma unroll
    for (int j = 0; j < 8; ++j) acc[j] = 0.f;
#pragma unroll
    for (int s = 0; s < 2; ++s) {
        int hsm = tid + s * 256;
        float hid = fmaxf(0.f, t0 * w1[hsm] + t1 * w1[512 + hsm] + b1[hsm]);
#pragma unroll
        for (int j = 0; j < 8; ++j) acc[j] += hid * w2[hsm * 8 + j];
    }
#pragma unroll
    for (int off = 1; off < 64; off <<= 1)
#pragma unroll
        for (int j = 0; j < 8; ++j) acc[j] += __shfl_xor(acc[j], off, 64);
    __shared__ float red[4][8];
    if (lane == 0)
#pragma unroll
        for (int j = 0; j < 8; ++j) red[wid][j] = acc[j];
    __syncthreads();
    if (tid < 8)
        b225g[e * 8 + tid] = red[0][tid] + red[1][tid] + red[2][tid] + red[3][tid];
}

// ---------------- K0c: expand to per-head 64x64 bias, TRANSPOSED [h][j][i] ----------------
__global__ __launch_bounds__(256) void bias_expand(const float* __restrict__ b225g,
                                                   float* __restrict__ bias_t) {
    int f = blockIdx.x * 256 + threadIdx.x;
    int h = f >> 12, ij = f & 4095, i = ij >> 6, j = ij & 63;
    int dh = (i >> 3) - (j >> 3), dw = (i & 7) - (j & 7);
    int e = (dh + 7) * 15 + (dw + 7);
    float v = b225g[e * 8 + h];
    // store transposed: row = j (key), col = i (query) -> softmax loads float4 along i
    bias_t[(h << 12) + j * 64 + i] = 16.f / (1.f + expf(-v));
}

// token row -> pixel (roll by +4 both ways, same map fwd/bwd)
__device__ __forceinline__ int row2pix(int row) {
    int w = row >> 6, t = row & 63;
    int b = w >> 6, wi = (w >> 3) & 7, wj = w & 7;
    int hh = (wi * 8 + (t >> 3) + 4) & 63;
    int ww = (wj * 8 + (t & 7) + 4) & 63;
    return (b * 64 + hh) * 64 + ww;
}

__device__ __forceinline__ int regid(int t, int wi, int wj) {
    int a = (wi < 7) ? 0 : (((t >> 3) < 4) ? 1 : 2);
    int b = (wj < 7) ? 0 : (((t & 7) < 4) ? 1 : 2);
    return a * 3 + b;
}

// ---------------- K0d: x -> bf16 token-fragment layout ----------------
// xbf: per (win, mt 0..3, kt 0..7) one 1KB frag: elem B[tok = mt*16+(lane&15)][k = kt*32+(lane>>4)*8+j]
// addr = ((win*4+mt)*8+kt)*512 + lane*8 + j
__global__ __launch_bounds__(256) void xtrans(const float* __restrict__ x,
                                              short* __restrict__ xbf) {
    int win = blockIdx.x;
    int tid = threadIdx.x;
    int r = tid >> 2, q = tid & 3;          // token r (0..63), channel quarter q
    const float* src = x + (size_t)row2pix(win * 64 + r) * 256 + q * 64;
    size_t fb = (size_t)(win * 4 + (r >> 4)) * 8;
    int l15r = r & 15;
#pragma unroll
    for (int kt2 = 0; kt2 < 2; ++kt2) {
        int kt = q * 2 + kt2;
        short* dst = xbf + (fb + kt) * 512 + l15r * 8;
#pragma unroll
        for (int quad = 0; quad < 4; ++quad) {
            float4 u0 = *(const float4*)(src + kt2 * 32 + quad * 8);
            float4 u1 = *(const float4*)(src + kt2 * 32 + quad * 8 + 4);
            shortx8 t;
            t[0] = f2bf(u0.x); t[1] = f2bf(u0.y); t[2] = f2bf(u0.z); t[3] = f2bf(u0.w);
            t[4] = f2bf(u1.x); t[5] = f2bf(u1.y); t[6] = f2bf(u1.z); t[7] = f2bf(u1.w);
            *(shortx8*)(dst + quad * 128) = t;
        }
    }
}

// ---------------- Fused: QKV gemm + attention + O-proj, one block per window ----------------
// 4 waves; wave w handles heads 2w (pass 0) and 2w+1 (pass 1).
// QKV C^T: acc = mfma(weight_frag, token_frag) -> rows=channel, cols=token.
// Token frags come pre-converted from xbf (16B loads, L2-hot). Per-pass O packed to bf16 regs.
// Wave-private LDS: qn[64][40], kn[64][40], vt[32][72], P[64][72] (aliases qn/kn). 7424 shorts/wave.
__global__ __launch_bounds__(256, 2) void swin_fused(const short* __restrict__ xbf,
                                                     const short* __restrict__ wf,
                                                     const short* __restrict__ wof,
                                                     const float* __restrict__ bq,
                                                     const float* __restrict__ bk_,
                                                     const float* __restrict__ bv,
                                                     const float* __restrict__ bo,
                                                     const float* __restrict__ bias_t,
                                                     const float* __restrict__ scale,
                                                     float* __restrict__ out) {
    __shared__ __align__(16) short lds[29696];   // 59392 B = 4 waves x 7424 shorts
    int tid = threadIdx.x, lane = tid & 63, wid = tid >> 6;
    int quad = lane >> 4, l15 = lane & 15;
    int win = blockIdx.x;
    int wi = (win >> 3) & 7, wj = win & 7;
    bool need_mask = (wi == 7) || (wj == 7);

    short* qn = &lds[wid * 7424];        // [64][40]
    short* kn = qn + 2560;               // [64][40]
    short* vt = qn + 5120;               // [32][72]
    short* P  = qn;                      // [64][72] aliases qn+kn after frags read

    const short* xfb = xbf + (size_t)(win * 4) * 8 * 512 + lane * 8;

    shortx4 Obf[2][4][2];                // per-pass attn output, bf16-packed

#pragma unroll
    for (int p = 0; p < 2; ++p) {
        int h = wid * 2 + p;
        // ---- QKV GEMM (C^T): 24 MFMA per kt ----
        floatx4 aq[2][4], ak[2][4], av[2][4];
#pragma unroll
        for (int i = 0; i < 2; ++i)
#pragma unroll
            for (int mt = 0; mt < 4; ++mt) {
                aq[i][mt] = (floatx4){0.f, 0.f, 0.f, 0.f};
                ak[i][mt] = (floatx4){0.f, 0.f, 0.f, 0.f};
                av[i][mt] = (floatx4){0.f, 0.f, 0.f, 0.f};
            }
#pragma unroll
        for (int kt = 0; kt < 8; ++kt) {
            shortx8 af[4];
#pragma unroll
            for (int mt = 0; mt < 4; ++mt)
                af[mt] = *(const shortx8*)(xfb + (size_t)(mt * 8 + kt) * 512);
            shortx8 wqf[2], wkf[2], wvf[2];
#pragma unroll
            for (int i = 0; i < 2; ++i) {
                int n16 = 2 * h + i;
                wqf[i] = *(const shortx8*)(wf + (size_t)((n16)*8 + kt) * 512 + lane * 8);
                wkf[i] = *(const shortx8*)(wf + (size_t)((16 + n16) * 8 + kt) * 512 + lane * 8);
                wvf[i] = *(const shortx8*)(wf + (size_t)((32 + n16) * 8 + kt) * 512 + lane * 8);
            }
#pragma unroll
            for (int i = 0; i < 2; ++i)
#pragma unroll
                for (int mt = 0; mt < 4; ++mt) {
                    aq[i][mt] = __builtin_amdgcn_mfma_f32_16x16x32_bf16(wqf[i], af[mt], aq[i][mt], 0, 0, 0);
                    ak[i][mt] = __builtin_amdgcn_mfma_f32_16x16x32_bf16(wkf[i], af[mt], ak[i][mt], 0, 0, 0);
                    av[i][mt] = __builtin_amdgcn_mfma_f32_16x16x32_bf16(wvf[i], af[mt], av[i][mt], 0, 0, 0);
                }
        }
        // ---- bias + cosine norms (token = col; sum over quads via shfl) ----
        float sc = scale[h];
        float qs[4], ks[4];
#pragma unroll
        for (int mt = 0; mt < 4; ++mt) { qs[mt] = 0.f; ks[mt] = 0.f; }
#pragma unroll
        for (int i = 0; i < 2; ++i) {
            float bqv[4], bkv[4], bvv[4];
#pragma unroll
            for (int r = 0; r < 4; ++r) {
                int d = i * 16 + quad * 4 + r;
                bqv[r] = bq[h * 32 + d];
                bkv[r] = bk_[h * 32 + d];
                bvv[r] = bv[h * 32 + d];
            }
#pragma unroll
            for (int mt = 0; mt < 4; ++mt)
#pragma unroll
                for (int r = 0; r < 4; ++r) {
                    float qv = aq[i][mt][r] + bqv[r]; aq[i][mt][r] = qv; qs[mt] += qv * qv;
                    float kv = ak[i][mt][r] + bkv[r]; ak[i][mt][r] = kv; ks[mt] += kv * kv;
                    av[i][mt][r] += bvv[r];
                }
        }
#pragma unroll
        for (int mt = 0; mt < 4; ++mt) {
            qs[mt] += __shfl_xor(qs[mt], 16, 64); qs[mt] += __shfl_xor(qs[mt], 32, 64);
            ks[mt] += __shfl_xor(ks[mt], 16, 64); ks[mt] += __shfl_xor(ks[mt], 32, 64);
        }
        CFENCE();
        // ---- write normalized q,k and transposed v into wave-private LDS ----
#pragma unroll
        for (int mt = 0; mt < 4; ++mt) {
            float qr = sc / fmaxf(sqrtf(qs[mt]), 1e-12f);
            float kr = 1.f / fmaxf(sqrtf(ks[mt]), 1e-12f);
            int tok = mt * 16 + l15;
#pragma unroll
            for (int i = 0; i < 2; ++i) {
                shortx4 oq, ok;
#pragma unroll
                for (int r = 0; r < 4; ++r) {
                    oq[r] = f2bf(aq[i][mt][r] * qr);
                    ok[r] = f2bf(ak[i][mt][r] * kr);
                }
                *(shortx4*)&qn[tok * 40 + i * 16 + quad * 4] = oq;
                *(shortx4*)&kn[tok * 40 + i * 16 + quad * 4] = ok;
#pragma unroll
                for (int r = 0; r < 4; ++r)
                    vt[(i * 16 + quad * 4 + r) * 72 + tok] = f2bf(av[i][mt][r]);
            }
        }
        CFENCE();
        // ---- QK^T ----
        shortx8 aqf[4], bkf[4];
#pragma unroll
        for (int mt = 0; mt < 4; ++mt)
            aqf[mt] = *(const shortx8*)&qn[(mt * 16 + l15) * 40 + quad * 8];
#pragma unroll
        for (int nt = 0; nt < 4; ++nt)
            bkf[nt] = *(const shortx8*)&kn[(nt * 16 + l15) * 40 + quad * 8];
        floatx4 S[4][4];
#pragma unroll
        for (int mt = 0; mt < 4; ++mt)
#pragma unroll
            for (int nt = 0; nt < 4; ++nt) {
                floatx4 z = {0.f, 0.f, 0.f, 0.f};
                S[mt][nt] = __builtin_amdgcn_mfma_f32_16x16x32_bf16(aqf[mt], bkf[nt], z, 0, 0, 0);
            }
        // ---- softmax (bias via transposed float4 loads) ----
        const float* bh = bias_t + (h << 12);
        float bound = sc + 16.5f;
        int jid[4];
        if (need_mask) {
#pragma unroll
            for (int nt = 0; nt < 4; ++nt) jid[nt] = regid(nt * 16 + l15, wi, wj);
        }
        float rs[4][4];
#pragma unroll
        for (int mt = 0; mt < 4; ++mt) {
            float4 b4[4];
#pragma unroll
            for (int nt = 0; nt < 4; ++nt)
                b4[nt] = *(const float4*)&bh[(nt * 16 + l15) * 64 + mt * 16 + quad * 4];
#pragma unroll
            for (int reg = 0; reg < 4; ++reg) {
                int i = mt * 16 + quad * 4 + reg;
                int iid = need_mask ? regid(i, wi, wj) : 0;
                float rowsum = 0.f;
#pragma unroll
                for (int nt = 0; nt < 4; ++nt) {
                    float bb = (reg == 0) ? b4[nt].x : (reg == 1) ? b4[nt].y
                             : (reg == 2) ? b4[nt].z : b4[nt].w;
                    float v = S[mt][nt][reg] + bb;
                    if (need_mask && iid != jid[nt]) v -= 100.f;
                    float pe = __expf(v - bound);
                    S[mt][nt][reg] = pe;
                    rowsum += pe;
                }
                rowsum += __shfl_xor(rowsum, 1, 64);
                rowsum += __shfl_xor(rowsum, 2, 64);
                rowsum += __shfl_xor(rowsum, 4, 64);
                rowsum += __shfl_xor(rowsum, 8, 64);
                rs[mt][reg] = 1.f / rowsum;
            }
        }
        CFENCE();
        // ---- P to LDS (aliases qn/kn; frags already consumed) ----
#pragma unroll
        for (int mt = 0; mt < 4; ++mt)
#pragma unroll
            for (int nt = 0; nt < 4; ++nt)
#pragma unroll
                for (int reg = 0; reg < 4; ++reg)
                    P[(mt * 16 + quad * 4 + reg) * 72 + nt * 16 + l15] = f2bf(S[mt][nt][reg]);
        CFENCE();
        // ---- PV ----
        floatx4 O[4][2];
#pragma unroll
        for (int mt = 0; mt < 4; ++mt)
#pragma unroll
            for (int nt = 0; nt < 2; ++nt) O[mt][nt] = (floatx4){0.f, 0.f, 0.f, 0.f};
#pragma unroll
        for (int ks2 = 0; ks2 < 2; ++ks2) {
            shortx8 pa[4], vb[2];
#pragma unroll
            for (int mt = 0; mt < 4; ++mt)
                pa[mt] = *(const shortx8*)&P[(mt * 16 + l15) * 72 + ks2 * 32 + quad * 8];
#pragma unroll
            for (int nt = 0; nt < 2; ++nt)
                vb[nt] = *(const shortx8*)&vt[(nt * 16 + l15) * 72 + ks2 * 32 + quad * 8];
#pragma unroll
            for (int mt = 0; mt < 4; ++mt)
#pragma unroll
                for (int nt = 0; nt < 2; ++nt)
                    O[mt][nt] = __builtin_amdgcn_mfma_f32_16x16x32_bf16(pa[mt], vb[nt], O[mt][nt], 0, 0, 0);
        }
        // ---- scale + pack to bf16 immediately (no fp32 held across passes) ----
#pragma unroll
        for (int mt = 0; mt < 4; ++mt)
#pragma unroll
            for (int nt = 0; nt < 2; ++nt) {
                shortx4 s;
#pragma unroll
                for (int reg = 0; reg < 4; ++reg)
                    s[reg] = f2bf(O[mt][nt][reg] * rs[mt][reg]);
                Obf[p][mt][nt] = s;
            }
        CFENCE();
    }

    // ---- gather attn outputs into shared Ao[64][264], then O-proj ----
    __syncthreads();
    short* Ao = lds;
#pragma unroll
    for (int p = 0; p < 2; ++p) {
        int h = wid * 2 + p;
#pragma unroll
        for (int mt = 0; mt < 4; ++mt)
#pragma unroll
            for (int nt = 0; nt < 2; ++nt)
#pragma unroll
                for (int reg = 0; reg < 4; ++reg)
                    Ao[(mt * 16 + quad * 4 + reg) * 264 + h * 32 + nt * 16 + l15] =
                        Obf[p][mt][nt][reg];
    }
    __syncthreads();

    int pix[4];
#pragma unroll
    for (int mt = 0; mt < 4; ++mt) pix[mt] = row2pix(win * 64 + mt * 16 + l15);

    floatx4 acc2[4][4];   // [nt][mt]
#pragma unroll
    for (int nt = 0; nt < 4; ++nt)
#pragma unroll
        for (int mt = 0; mt < 4; ++mt) acc2[nt][mt] = (floatx4){0.f, 0.f, 0.f, 0.f};
#pragma unroll
    for (int kt = 0; kt < 8; ++kt) {
        shortx8 bw[4], af2[4];
#pragma unroll
        for (int nt = 0; nt < 4; ++nt)
            bw[nt] = *(const shortx8*)(wof + (size_t)((wid * 4 + nt) * 8 + kt) * 512 + lane * 8);
#pragma unroll
        for (int mt = 0; mt < 4; ++mt)
            af2[mt] = *(const shortx8*)&Ao[(mt * 16 + l15) * 264 + kt * 32 + quad * 8];
#pragma unroll
        for (int nt = 0; nt < 4; ++nt)
#pragma unroll
            for (int mt = 0; mt < 4; ++mt)
                acc2[nt][mt] = __builtin_amdgcn_mfma_f32_16x16x32_bf16(bw[nt], af2[mt], acc2[nt][mt], 0, 0, 0);
    }
#pragma unroll
    for (int nt = 0; nt < 4; ++nt) {
        int nb = wid * 64 + nt * 16 + quad * 4;
        float bs[4];
#pragma unroll
        for (int reg = 0; reg < 4; ++reg) bs[reg] = bo[nb + reg];
#pragma unroll
        for (int mt = 0; mt < 4; ++mt) {
            float4 o;
            o.x = acc2[nt][mt][0] + bs[0];
            o.y = acc2[nt][mt][1] + bs[1];
            o.z = acc2[nt][mt][2] + bs[2];
            o.w = acc2[nt][mt][3] + bs[3];
            *(float4*)(out + (size_t)pix[mt] * 256 + nb) = o;
        }
    }
}

// ---------------- launch ----------------
extern "C" void kernel_launch(void* const* d_in, const int* in_sizes, int n_in,
                              void* d_out, int out_size, void* d_ws, size_t ws_size,
                              hipStream_t stream) {
    const float* x  = (const float*)d_in[0];
    const float* Wq = (const float*)d_in[1];
    const float* bq = (const float*)d_in[2];
    const float* Wk = (const float*)d_in[3];
    const float* bk = (const float*)d_in[4];
    const float* Wv = (const float*)d_in[5];
    const float* bv = (const float*)d_in[6];
    const float* Wo = (const float*)d_in[7];
    const float* bo = (const float*)d_in[8];
    const float* ls = (const float*)d_in[9];
    const float* w1 = (const float*)d_in[10];
    const float* b1 = (const float*)d_in[11];
    const float* w2 = (const float*)d_in[12];

    char* ws = (char*)d_ws;
    short* wqkv_f = (short*)(ws + 0);           //   393,216 B
    short* wo_f   = (short*)(ws + 393216);      //   131,072 B
    float* bias_t = (float*)(ws + 524288);      //   131,072 B
    float* scale  = (float*)(ws + 655360);      //        32 B
    float* b225g  = (float*)(ws + 786432);      //     7,200 B
    short* xbf    = (short*)(ws + 1048576);     //  33,554,432 B
    float* out    = (float*)d_out;

    hipLaunchKernelGGL(wtrans, dim3(128), dim3(256), 0, stream, Wq, Wk, Wv, Wo, wqkv_f, wo_f);
    hipLaunchKernelGGL(bias_mlp, dim3(225), dim3(256), 0, stream, ls, w1, b1, w2, b225g, scale);
    hipLaunchKernelGGL(bias_expand, dim3(128), dim3(256), 0, stream, b225g, bias_t);
    hipLaunchKernelGGL(xtrans, dim3(1024), dim3(256), 0, stream, x, xbf);
    hipLaunchKernelGGL(swin_fused, dim3(1024), dim3(256), 0, stream,
                       xbf, wqkv_f, wo_f, bq, bk, bv, bo, bias_t, scale, out);
}